// Round 9
// baseline (131.059 us; speedup 1.0000x reference)
//
#include <hip/hip_runtime.h>
#include <hip/hip_fp16.h>

#define N 32768
#define P 8192
#define XT 16                               // x per block = MFMA m-dim
#define WAVES 4                             // pattern phases per block
#define THREADS (WAVES * 64)                // 256
#define NBLK (N / XT)                       // 2048
#define CHUNK 32                            // patterns per MFMA (K dim)
#define CPW (P / WAVES / CHUNK)             // 64 chunks per wave

// f = log2(e)/(2*sigma^2), sigma^2 = 1.44; per-x |x|^2 cancels in num/den.
#define RBF_F 0.50093577808645257f

typedef _Float16 h2  __attribute__((ext_vector_type(2)));
typedef _Float16 v8h __attribute__((ext_vector_type(8)));
typedef float    v4f __attribute__((ext_vector_type(4)));

// QA: one 16-B record per pattern-pair p2=(2q,2q+1):
//   { c0a,c0b, c1a,c1b, c2a,c2b, 0,0 }  (f16; c0=2f*p0, c1=2f*p1, c2=-f*|p|^2)
// WH: w2 in f16, one per pattern.
__global__ void prep_kernel(const float* __restrict__ pat,
                            const float* __restrict__ w2,
                            _Float16* __restrict__ QA,
                            _Float16* __restrict__ WH) {
    int q = blockIdx.x * blockDim.x + threadIdx.x;
    if (q < P / 2) {
        float p00 = pat[4 * q + 0], p01 = pat[4 * q + 1];
        float p10 = pat[4 * q + 2], p11 = pat[4 * q + 3];
        v8h r;
        r[0] = (_Float16)(2.0f * RBF_F * p00);
        r[1] = (_Float16)(2.0f * RBF_F * p10);
        r[2] = (_Float16)(2.0f * RBF_F * p01);
        r[3] = (_Float16)(2.0f * RBF_F * p11);
        r[4] = (_Float16)(-RBF_F * (p00 * p00 + p01 * p01));
        r[5] = (_Float16)(-RBF_F * (p10 * p10 + p11 * p11));
        r[6] = (_Float16)0.0f;
        r[7] = (_Float16)0.0f;
        ((v8h*)QA)[q] = r;
        WH[2 * q]     = (_Float16)w2[2 * q];
        WH[2 * q + 1] = (_Float16)w2[2 * q + 1];
    }
}

__global__ __launch_bounds__(THREADS) void
rbf_kernel(const float* __restrict__ X,
           const _Float16* __restrict__ QA,
           const _Float16* __restrict__ WH,
           float* __restrict__ out) {
    const int t    = threadIdx.x;
    const int lane = t & 63;
    const int wv   = __builtin_amdgcn_readfirstlane(t >> 6);  // phase 0..3
    const int n16  = lane & 15;          // MFMA n (B col); also this lane's x (A m)
    const int quad = lane >> 4;          // selects the lane's 8-pattern k-group

    // per-lane x (A-operand row m = lane&15), as f16 splat pairs
    const float2 xv = ((const float2*)X)[blockIdx.x * XT + n16];
    const __half2 xx0 = __float2half2_rn(xv.x);
    const __half2 xx1 = __float2half2_rn(xv.y);

    // B template: col n==1 -> 1.0 (den), others 0 (col 0 overwritten by w)
    v8h btpl;
#pragma unroll
    for (int j = 0; j < 8; ++j)
        btpl[j] = (n16 == 1) ? (_Float16)1.0f : (_Float16)0.0f;

    v4f acc = {0.f, 0.f, 0.f, 0.f};

    // pair index base for this wave's phase: chunk ch -> pb + ch*16 + u
    const v8h* __restrict__ QA8 = (const v8h*)QA;
    const int pb = (wv * CPW) * 16 + quad * 4;
    const _Float16* __restrict__ WB = WH + (wv * CPW) * 32 + quad * 8;

    auto cell2 = [&](v8h q) -> __half2 {   // 2 kernel values per record
        __half2 c0 = __builtin_bit_cast(__half2, (h2)__builtin_shufflevector(q, q, 0, 1));
        __half2 c1 = __builtin_bit_cast(__half2, (h2)__builtin_shufflevector(q, q, 2, 3));
        __half2 c2 = __builtin_bit_cast(__half2, (h2)__builtin_shufflevector(q, q, 4, 5));
        __half2 tt = __hfma2(c0, xx0, __hfma2(c1, xx1, c2));  // v_pk_fma_f16
        return h2exp2(tt);                                     // 2x v_exp_f16
    };

    // depth-1 prefetch (wrapped)
    v8h qc0 = QA8[pb + 0], qc1 = QA8[pb + 1], qc2 = QA8[pb + 2], qc3 = QA8[pb + 3];
    v8h bc = btpl;
    if (n16 == 0) bc = *(const v8h*)WB;

#pragma unroll 2
    for (int ch = 0; ch < CPW; ++ch) {
        const int chn = (ch + 1) & (CPW - 1);
        v8h qn0 = QA8[pb + chn * 16 + 0];
        v8h qn1 = QA8[pb + chn * 16 + 1];
        v8h qn2 = QA8[pb + chn * 16 + 2];
        v8h qn3 = QA8[pb + chn * 16 + 3];
        v8h bn = btpl;
        if (n16 == 0) bn = *(const v8h*)(WB + chn * 32);

        __half2 k0 = cell2(qc0), k1 = cell2(qc1), k2 = cell2(qc2), k3 = cell2(qc3);
        h2 k0h = __builtin_bit_cast(h2, k0);
        h2 k1h = __builtin_bit_cast(h2, k1);
        h2 k2h = __builtin_bit_cast(h2, k2);
        h2 k3h = __builtin_bit_cast(h2, k3);
        v8h a;
        a[0] = k0h.x; a[1] = k0h.y; a[2] = k1h.x; a[3] = k1h.y;
        a[4] = k2h.x; a[5] = k2h.y; a[6] = k3h.x; a[7] = k3h.y;

        // D[m=x][n]: n=0 accumulates num (w col), n=1 den (ones col), fp32
        acc = __builtin_amdgcn_mfma_f32_16x16x32_f16(a, bc, acc, 0, 0, 0);

        qc0 = qn0; qc1 = qn1; qc2 = qn2; qc3 = qn3; bc = bn;
    }

    // C/D layout: col=lane&15 (n), row=(lane>>4)*4+reg (m=x)
    __shared__ float red[WAVES][XT][2];
    if (n16 < 2) {
#pragma unroll
        for (int r = 0; r < 4; ++r)
            red[wv][quad * 4 + r][n16] = acc[r];
    }
    __syncthreads();

    if (t < XT) {
        float nn = 0.f, dd = 0.f;
#pragma unroll
        for (int w = 0; w < WAVES; ++w) {
            nn += red[w][t][0];
            dd += red[w][t][1];
        }
        out[blockIdx.x * XT + t] = nn / dd;
    }
}

extern "C" void kernel_launch(void* const* d_in, const int* in_sizes, int n_in,
                              void* d_out, int out_size, void* d_ws, size_t ws_size,
                              hipStream_t stream) {
    const float* X   = (const float*)d_in[0];   // [32768, 2]
    const float* pat = (const float*)d_in[1];   // [8192, 2]
    const float* w2  = (const float*)d_in[2];   // [8192]
    float* out = (float*)d_out;                 // [32768]

    _Float16* QA = (_Float16*)d_ws;             // P/2 pairs * 16 B = 64 KB
    _Float16* WH = QA + (size_t)P * 4;          // P * 2 B = 16 KB

    prep_kernel<<<(P / 2 + 255) / 256, 256, 0, stream>>>(pat, w2, QA, WH);
    rbf_kernel<<<NBLK, THREADS, 0, stream>>>(X, QA, WH, out);
}